// Round 4
// baseline (457.880 us; speedup 1.0000x reference)
//
#include <hip/hip_runtime.h>

#define DIM 96
#define NBINS 64
#define BSZ 15
#define PADROWS (DIM + BSZ - 1)   /* 110 */
#define C4N 16                    /* float4 per bin-row = 64/4 */
#define RS4 17                    /* padded row stride in float4 (K1 LDS) */
#define NTHREADS 256
#define PPS 6                     /* positions per strip in K1 */

// ---------------------------------------------------------------------------
// K1: per-(z,y) line. Gradients -> soft binning into LDS V[110][64] -> forward
// sliding-window sum (15) along x -> write out[z][y][x][64].  (unchanged)
// ---------------------------------------------------------------------------
__global__ __launch_bounds__(NTHREADS) void k_bin_xsum(
    const float* __restrict__ in, float* __restrict__ out)
{
    __shared__ float4 V4[PADROWS * RS4];
    float* Vf = (float*)V4;
    const int tid = threadIdx.x;
    const int y = blockIdx.x;
    const int z = blockIdx.y;

    for (int i = tid; i < PADROWS * RS4; i += NTHREADS)
        V4[i] = make_float4(0.f, 0.f, 0.f, 0.f);
    __syncthreads();

    if (tid < DIM) {
        const int x = tid;
        const int idx = (z * DIM + y) * DIM + x;
        const float xm = (x > 0)       ? in[idx - 1]         : 0.0f;
        const float xp = (x < DIM - 1) ? in[idx + 1]         : 0.0f;
        const float ym = (y > 0)       ? in[idx - DIM]       : 0.0f;
        const float yp = (y < DIM - 1) ? in[idx + DIM]       : 0.0f;
        const float zm = (z > 0)       ? in[idx - DIM * DIM] : 0.0f;
        const float zp = (z < DIM - 1) ? in[idx + DIM * DIM] : 0.0f;
        const float gx = xp - xm, gy = yp - ym, gz = zp - zm;

        const float EPSF  = 2.220446049250313e-16f;
        const float TWOPI = 6.28318530717958647692f;
        const float PIF   = 3.14159265358979323846f;

        const float r = sqrtf(gx * gx + gy * gy + gz * gz);
        float theta = atanf(gy / (gx + EPSF));
        const float phi = acosf(gz / (r + EPSF));
        if (theta < 0.0f) theta += TWOPI;
        const float t_raw = theta / (TWOPI / 8.0f);
        const float p_raw = phi   / (PIF   / 8.0f);
        const float ft = floorf(t_raw);
        const float fp = floorf(p_raw);
        int lt = (int)ft; if (lt == 8) lt = 0;
        int lp = (int)fp; if (lp == 8) lp = 0;
        const int ht = (lt + 1) & 7;
        const int hp = (lp + 1) & 7;
        const float frac  = t_raw - ft;
        const float w_lo  = fminf(frac, 1.0f - frac);
        const float w_hi  = 1.0f - w_lo;
        const float wp_lo = (frac == 0.0f) ? 1.0f : w_lo;  // faithful: theta frac gates phi split
        const float wp_hi = 1.0f - wp_lo;

        float* vrow = Vf + x * (RS4 * 4);
        vrow[lt * 8 + lp] += r * w_lo * wp_lo;
        vrow[ht * 8 + lp] += r * w_hi * wp_lo;
        vrow[lt * 8 + hp] += r * w_lo * wp_hi;
        vrow[ht * 8 + hp] += r * w_hi * wp_hi;
    }
    __syncthreads();

    const int c4    = tid & (C4N - 1);
    const int strip = tid >> 4;
    int pos = strip * PPS;

    float4 s = make_float4(0.f, 0.f, 0.f, 0.f);
    #pragma unroll
    for (int d = 0; d < BSZ; ++d) {
        const float4 v = V4[(pos + d) * RS4 + c4];
        s.x += v.x; s.y += v.y; s.z += v.z; s.w += v.w;
    }
    float4* out4 = (float4*)out;
    const int base = (z * DIM + y) * DIM * C4N;
    out4[base + pos * C4N + c4] = s;
    #pragma unroll
    for (int j = 1; j < PPS; ++j) {
        const float4 a = V4[pos * RS4 + c4];
        const float4 b = V4[(pos + BSZ) * RS4 + c4];
        s.x += b.x - a.x; s.y += b.y - a.y; s.z += b.z - a.z; s.w += b.w - a.w;
        ++pos;
        out4[base + pos * C4N + c4] = s;
    }
}

// ---------------------------------------------------------------------------
// K2/K3 (src != dst): pure-streaming forward sliding-window sum of 15 along
// an axis. Each thread owns one (line, x, c4) float4-column; a 256-thread
// block covers 16 consecutive x * 16 c4 = 4KB contiguous per pos-step.
// No LDS, no barriers. Line split across gridDim.z blocks (safe: src!=dst).
//   addr4(pos) = line*lineMul + x*16 + c4 + pos*stride4
// ---------------------------------------------------------------------------
__global__ __launch_bounds__(NTHREADS) void k_axis_stream_rr(
    const float* __restrict__ src, float* __restrict__ dst,
    const int lineMul, const int stride4)
{
    const int tid = threadIdx.x;
    const int c4 = tid & (C4N - 1);
    const int xl = tid >> 4;
    const int x  = blockIdx.x * 16 + xl;
    const float4* __restrict__ s4 = (const float4*)src;
    float4* __restrict__ d4 = (float4*)dst;
    const size_t base4 = (size_t)blockIdx.y * lineMul + (size_t)x * C4N + c4;
    const int pblk = DIM / gridDim.z;
    const int p0 = blockIdx.z * pblk;

    float4 s = make_float4(0.f, 0.f, 0.f, 0.f);
    #pragma unroll
    for (int j = 0; j < BSZ - 1; ++j) {           // p0 <= 48 -> p0+13 < 96 always
        const float4 v = s4[base4 + (size_t)(p0 + j) * stride4];
        s.x += v.x; s.y += v.y; s.z += v.z; s.w += v.w;
    }
    #pragma unroll 4
    for (int i = 0; i < pblk; ++i) {
        const int p = p0 + i;
        const size_t ap = base4 + (size_t)p * stride4;
        if (p + BSZ - 1 < DIM) {
            const float4 v = s4[ap + (size_t)(BSZ - 1) * stride4];
            s.x += v.x; s.y += v.y; s.z += v.z; s.w += v.w;
        }
        const float4 vsub = s4[ap];
        d4[ap] = s;
        s.x -= vsub.x; s.y -= vsub.y; s.z -= vsub.z; s.w -= vsub.w;
    }
}

// In-place fallback (no __restrict__ aliasing lies; one block per full line,
// per-thread read-before-write ordering makes in-place safe, no barriers).
__global__ __launch_bounds__(NTHREADS) void k_axis_stream_ip(
    float* data, const int lineMul, const int stride4)
{
    const int tid = threadIdx.x;
    const int c4 = tid & (C4N - 1);
    const int xl = tid >> 4;
    const int x  = blockIdx.x * 16 + xl;
    float4* d4 = (float4*)data;
    const size_t base4 = (size_t)blockIdx.y * lineMul + (size_t)x * C4N + c4;

    float4 s = make_float4(0.f, 0.f, 0.f, 0.f);
    #pragma unroll
    for (int j = 0; j < BSZ - 1; ++j) {
        const float4 v = d4[base4 + (size_t)j * stride4];
        s.x += v.x; s.y += v.y; s.z += v.z; s.w += v.w;
    }
    #pragma unroll 4
    for (int p = 0; p < DIM; ++p) {
        const size_t ap = base4 + (size_t)p * stride4;
        if (p + BSZ - 1 < DIM) {
            const float4 v = d4[ap + (size_t)(BSZ - 1) * stride4];
            s.x += v.x; s.y += v.y; s.z += v.z; s.w += v.w;
        }
        const float4 vsub = d4[ap];
        d4[ap] = s;
        s.x -= vsub.x; s.y -= vsub.y; s.z -= vsub.z; s.w -= vsub.w;
    }
}

extern "C" void kernel_launch(void* const* d_in, const int* in_sizes, int n_in,
                              void* d_out, int out_size, void* d_ws, size_t ws_size,
                              hipStream_t stream) {
    (void)in_sizes; (void)n_in; (void)out_size;
    const float* x = (const float*)d_in[0];
    float* out = (float*)d_out;
    float* ws = (float*)d_ws;
    const size_t need = (size_t)DIM * DIM * DIM * NBINS * sizeof(float);

    dim3 block(NTHREADS);
    // Pass 1: binning + x-axis window, writes every output element of `out`
    k_bin_xsum<<<dim3(DIM, DIM), block, 0, stream>>>(x, out);

    if (ws_size >= need) {
        // Pass 2 (y): out -> ws. line=z: base z*96*96*16, step y = 96*16
        k_axis_stream_rr<<<dim3(6, DIM, 2), block, 0, stream>>>(
            out, ws, DIM * DIM * C4N, DIM * C4N);
        // Pass 3 (z): ws -> out. line=y: base y*96*16, step z = 96*96*16
        k_axis_stream_rr<<<dim3(6, DIM, 2), block, 0, stream>>>(
            ws, out, DIM * C4N, DIM * DIM * C4N);
    } else {
        // In-place fallback, one block per full line
        k_axis_stream_ip<<<dim3(6, DIM, 1), block, 0, stream>>>(
            out, DIM * DIM * C4N, DIM * C4N);
        k_axis_stream_ip<<<dim3(6, DIM, 1), block, 0, stream>>>(
            out, DIM * C4N, DIM * DIM * C4N);
    }
}

// Round 5
// 411.198 us; speedup vs baseline: 1.1135x; 1.1135x over previous
//
#include <hip/hip_runtime.h>

#define DIM 96
#define NBINS 64
#define BSZ 15
#define PADROWS (DIM + BSZ - 1)   /* 110 */
#define C4N 16                    /* float4 per bin-row = 64/4 */
#define RS4 17                    /* padded row stride in float4 (K1 LDS) */
#define NTHREADS 256
#define PPS 6                     /* positions per strip in K1 */

// ---------------------------------------------------------------------------
// K1: per-(z,y) line. Gradients -> soft binning into LDS V[110][64] -> forward
// sliding-window sum (15) along x -> write out[z][y][x][64].  (unchanged)
// ---------------------------------------------------------------------------
__global__ __launch_bounds__(NTHREADS) void k_bin_xsum(
    const float* __restrict__ in, float* __restrict__ out)
{
    __shared__ float4 V4[PADROWS * RS4];
    float* Vf = (float*)V4;
    const int tid = threadIdx.x;
    const int y = blockIdx.x;
    const int z = blockIdx.y;

    for (int i = tid; i < PADROWS * RS4; i += NTHREADS)
        V4[i] = make_float4(0.f, 0.f, 0.f, 0.f);
    __syncthreads();

    if (tid < DIM) {
        const int x = tid;
        const int idx = (z * DIM + y) * DIM + x;
        const float xm = (x > 0)       ? in[idx - 1]         : 0.0f;
        const float xp = (x < DIM - 1) ? in[idx + 1]         : 0.0f;
        const float ym = (y > 0)       ? in[idx - DIM]       : 0.0f;
        const float yp = (y < DIM - 1) ? in[idx + DIM]       : 0.0f;
        const float zm = (z > 0)       ? in[idx - DIM * DIM] : 0.0f;
        const float zp = (z < DIM - 1) ? in[idx + DIM * DIM] : 0.0f;
        const float gx = xp - xm, gy = yp - ym, gz = zp - zm;

        const float EPSF  = 2.220446049250313e-16f;
        const float TWOPI = 6.28318530717958647692f;
        const float PIF   = 3.14159265358979323846f;

        const float r = sqrtf(gx * gx + gy * gy + gz * gz);
        float theta = atanf(gy / (gx + EPSF));
        const float phi = acosf(gz / (r + EPSF));
        if (theta < 0.0f) theta += TWOPI;
        const float t_raw = theta / (TWOPI / 8.0f);
        const float p_raw = phi   / (PIF   / 8.0f);
        const float ft = floorf(t_raw);
        const float fp = floorf(p_raw);
        int lt = (int)ft; if (lt == 8) lt = 0;
        int lp = (int)fp; if (lp == 8) lp = 0;
        const int ht = (lt + 1) & 7;
        const int hp = (lp + 1) & 7;
        const float frac  = t_raw - ft;
        const float w_lo  = fminf(frac, 1.0f - frac);
        const float w_hi  = 1.0f - w_lo;
        const float wp_lo = (frac == 0.0f) ? 1.0f : w_lo;  // faithful: theta frac gates phi split
        const float wp_hi = 1.0f - wp_lo;

        float* vrow = Vf + x * (RS4 * 4);
        vrow[lt * 8 + lp] += r * w_lo * wp_lo;
        vrow[ht * 8 + lp] += r * w_hi * wp_lo;
        vrow[lt * 8 + hp] += r * w_lo * wp_hi;
        vrow[ht * 8 + hp] += r * w_hi * wp_hi;
    }
    __syncthreads();

    const int c4    = tid & (C4N - 1);
    const int strip = tid >> 4;
    int pos = strip * PPS;

    float4 s = make_float4(0.f, 0.f, 0.f, 0.f);
    #pragma unroll
    for (int d = 0; d < BSZ; ++d) {
        const float4 v = V4[(pos + d) * RS4 + c4];
        s.x += v.x; s.y += v.y; s.z += v.z; s.w += v.w;
    }
    float4* out4 = (float4*)out;
    const int base = (z * DIM + y) * DIM * C4N;
    out4[base + pos * C4N + c4] = s;
    #pragma unroll
    for (int j = 1; j < PPS; ++j) {
        const float4 a = V4[pos * RS4 + c4];
        const float4 b = V4[(pos + BSZ) * RS4 + c4];
        s.x += b.x - a.x; s.y += b.y - a.y; s.z += b.z - a.z; s.w += b.w - a.w;
        ++pos;
        out4[base + pos * C4N + c4] = s;
    }
}

// ---------------------------------------------------------------------------
// K2/K3: IN-PLACE streaming forward sliding-window sum of 15 along an axis.
// No LDS, no barriers. One block per line (576 blocks) -- max race-free
// in-place parallelism. Each thread owns one (x,c4) float4-column and walks
// all 96 positions: read a[p] (and a[p+14]) BEFORE writing a[p]; columns are
// disjoint across threads, so in-place is safe. Block footprint per step =
// 4KB contiguous. Whole volume (226.5MB) stays L3-resident across passes.
//   addr4(pos) = line*lineMul + x*16 + c4 + pos*stride4
// ---------------------------------------------------------------------------
__global__ __launch_bounds__(NTHREADS) void k_axis_ip(
    float* data, const int lineMul, const int stride4)
{
    const int tid = threadIdx.x;
    const int c4 = tid & (C4N - 1);
    const int xl = tid >> 4;
    const int x  = blockIdx.x * 16 + xl;
    float4* d4 = (float4*)data;
    const size_t base = (size_t)blockIdx.y * lineMul + (size_t)x * C4N + c4;

    float4 s = make_float4(0.f, 0.f, 0.f, 0.f);
    // prologue: s = sum a[0..13]
    #pragma unroll
    for (int j = 0; j < BSZ - 1; ++j) {
        const float4 v = d4[base + (size_t)j * stride4];
        s.x += v.x; s.y += v.y; s.z += v.z; s.w += v.w;
    }
    // main: p = 0..81, full 15-windows (p+14 <= 95)
    #pragma unroll 6
    for (int p = 0; p <= DIM - BSZ; ++p) {
        const size_t ap = base + (size_t)p * stride4;
        const float4 add = d4[ap + (size_t)(BSZ - 1) * stride4];
        const float4 sub = d4[ap];                 // L1/L2 hit (read 14 steps ago)
        s.x += add.x; s.y += add.y; s.z += add.z; s.w += add.w;
        d4[ap] = s;
        s.x -= sub.x; s.y -= sub.y; s.z -= sub.z; s.w -= sub.w;
    }
    // tail: p = 82..95, truncated windows (no adds)
    #pragma unroll
    for (int p = DIM - BSZ + 1; p < DIM; ++p) {
        const size_t ap = base + (size_t)p * stride4;
        const float4 sub = d4[ap];
        d4[ap] = s;
        s.x -= sub.x; s.y -= sub.y; s.z -= sub.z; s.w -= sub.w;
    }
}

extern "C" void kernel_launch(void* const* d_in, const int* in_sizes, int n_in,
                              void* d_out, int out_size, void* d_ws, size_t ws_size,
                              hipStream_t stream) {
    (void)in_sizes; (void)n_in; (void)out_size; (void)d_ws; (void)ws_size;
    const float* x = (const float*)d_in[0];
    float* out = (float*)d_out;

    dim3 block(NTHREADS);
    // Pass 1: binning + x-axis window, writes every output element of `out`
    k_bin_xsum<<<dim3(DIM, DIM), block, 0, stream>>>(x, out);
    // Pass 2 (y): in place. line=z: base z*96*96*16, step y = 96*16 f4 (24KB)
    k_axis_ip<<<dim3(6, DIM), block, 0, stream>>>(out, DIM * DIM * C4N, DIM * C4N);
    // Pass 3 (z): in place. line=y: base y*96*16, step z = 96*96*16 f4 (2.25MB)
    k_axis_ip<<<dim3(6, DIM), block, 0, stream>>>(out, DIM * C4N, DIM * DIM * C4N);
}

// Round 6
// 335.481 us; speedup vs baseline: 1.3648x; 1.2257x over previous
//
#include <hip/hip_runtime.h>

typedef _Float16 half_t;
typedef __attribute__((ext_vector_type(8))) _Float16 half8;
typedef __attribute__((ext_vector_type(4))) _Float16 half4;

#define DIM 96
#define NBINS 64
#define BSZ 15
#define PADROWS (DIM + BSZ - 1)   /* 110 */
#define NTHREADS 256
#define RS_F 68                   /* f32 LDS row stride in floats (64+4 pad) */
#define RS4_F 17                  /* same, in float4 */
#define RS_H 72                   /* f16 LDS row stride in halves (64+8 pad) */

// ===========================================================================
// Shared device helper: gradient + faithful soft-binning of one (z,y) line
// into LDS rows V[x][bin] (f32). V must be zeroed; 96 lanes participate.
// ===========================================================================
__device__ __forceinline__ void bin_line_to_lds(
    const float* __restrict__ in, float* __restrict__ V,
    const int y, const int z, const int tid)
{
    if (tid < DIM) {
        const int x = tid;
        const int idx = (z * DIM + y) * DIM + x;
        const float xm = (x > 0)       ? in[idx - 1]         : 0.0f;
        const float xp = (x < DIM - 1) ? in[idx + 1]         : 0.0f;
        const float ym = (y > 0)       ? in[idx - DIM]       : 0.0f;
        const float yp = (y < DIM - 1) ? in[idx + DIM]       : 0.0f;
        const float zm = (z > 0)       ? in[idx - DIM * DIM] : 0.0f;
        const float zp = (z < DIM - 1) ? in[idx + DIM * DIM] : 0.0f;
        const float gx = xp - xm, gy = yp - ym, gz = zp - zm;

        const float EPSF  = 2.220446049250313e-16f;
        const float TWOPI = 6.28318530717958647692f;
        const float PIF   = 3.14159265358979323846f;

        const float r = sqrtf(gx * gx + gy * gy + gz * gz);
        float theta = atanf(gy / (gx + EPSF));
        const float phi = acosf(gz / (r + EPSF));
        if (theta < 0.0f) theta += TWOPI;
        const float t_raw = theta / (TWOPI / 8.0f);
        const float p_raw = phi   / (PIF   / 8.0f);
        const float ft = floorf(t_raw);
        const float fp = floorf(p_raw);
        int lt = (int)ft; if (lt == 8) lt = 0;
        int lp = (int)fp; if (lp == 8) lp = 0;
        const int ht = (lt + 1) & 7;
        const int hp = (lp + 1) & 7;
        const float frac  = t_raw - ft;
        const float w_lo  = fminf(frac, 1.0f - frac);
        const float w_hi  = 1.0f - w_lo;
        const float wp_lo = (frac == 0.0f) ? 1.0f : w_lo;  // faithful: theta frac gates phi split
        const float wp_hi = 1.0f - wp_lo;

        float* vrow = V + x * RS_F;
        vrow[lt * 8 + lp] += r * w_lo * wp_lo;
        vrow[ht * 8 + lp] += r * w_hi * wp_lo;
        vrow[lt * 8 + hp] += r * w_lo * wp_hi;
        vrow[ht * 8 + hp] += r * w_hi * wp_hi;
    }
}

// ===========================================================================
// K1h: bin + x-window -> fp16 ws1[z][y][x][64]
// threads: strip = tid>>3 (0..31, 3 pos each), c8 = tid&7 (8 bins each)
// ===========================================================================
__global__ __launch_bounds__(NTHREADS) void k1_bin_xsum_h(
    const float* __restrict__ in, half_t* __restrict__ ws1)
{
    __shared__ float V[PADROWS * RS_F];
    const int tid = threadIdx.x;
    const int y = blockIdx.x, z = blockIdx.y;

    for (int i = tid; i < PADROWS * RS4_F; i += NTHREADS)
        ((float4*)V)[i] = make_float4(0.f, 0.f, 0.f, 0.f);
    __syncthreads();
    bin_line_to_lds(in, V, y, z, tid);
    __syncthreads();

    const int c8 = tid & 7;
    const int strip = tid >> 3;          // 0..31
    int pos = strip * 3;
    const float4* V4 = (const float4*)V;

    float acc[8];
    #pragma unroll
    for (int k = 0; k < 8; ++k) acc[k] = 0.f;
    #pragma unroll
    for (int d = 0; d < BSZ; ++d) {
        const float4 a = V4[(pos + d) * RS4_F + c8 * 2];
        const float4 b = V4[(pos + d) * RS4_F + c8 * 2 + 1];
        acc[0] += a.x; acc[1] += a.y; acc[2] += a.z; acc[3] += a.w;
        acc[4] += b.x; acc[5] += b.y; acc[6] += b.z; acc[7] += b.w;
    }
    #pragma unroll
    for (int j = 0; j < 3; ++j) {
        half8 o;
        #pragma unroll
        for (int k = 0; k < 8; ++k) o[k] = (half_t)acc[k];
        *(half8*)(ws1 + (((size_t)(z * DIM + y) * DIM + pos) * NBINS + c8 * 8)) = o;
        if (j < 2) {
            const float4 a0 = V4[pos * RS4_F + c8 * 2];
            const float4 b0 = V4[pos * RS4_F + c8 * 2 + 1];
            const float4 a1 = V4[(pos + BSZ) * RS4_F + c8 * 2];
            const float4 b1 = V4[(pos + BSZ) * RS4_F + c8 * 2 + 1];
            acc[0] += a1.x - a0.x; acc[1] += a1.y - a0.y;
            acc[2] += a1.z - a0.z; acc[3] += a1.w - a0.w;
            acc[4] += b1.x - b0.x; acc[5] += b1.y - b0.y;
            acc[6] += b1.z - b0.z; acc[7] += b1.w - b0.w;
            ++pos;
        }
    }
}

// ===========================================================================
// K2h: y-window, fp16 ws1 -> fp16 ws2. Block per (x=bx, z=by), line = 96 y.
// ===========================================================================
__global__ __launch_bounds__(NTHREADS) void k2_ysum_h(
    const half_t* __restrict__ ws1, half_t* __restrict__ ws2)
{
    __shared__ half_t H[PADROWS * RS_H];
    const int tid = threadIdx.x;
    const int x = blockIdx.x, z = blockIdx.y;

    for (int i = tid; i < DIM * 8; i += NTHREADS) {
        const int pos = i >> 3, c8 = i & 7;
        *(half8*)&H[pos * RS_H + c8 * 8] =
            *(const half8*)(ws1 + (((size_t)(z * DIM + pos) * DIM + x) * NBINS + c8 * 8));
    }
    for (int i = tid; i < (PADROWS - DIM) * 8; i += NTHREADS) {
        const int pos = DIM + (i >> 3), c8 = i & 7;
        half8 zv = {};
        *(half8*)&H[pos * RS_H + c8 * 8] = zv;
    }
    __syncthreads();

    const int c8 = tid & 7;
    const int strip = tid >> 3;
    int pos = strip * 3;

    float acc[8];
    #pragma unroll
    for (int k = 0; k < 8; ++k) acc[k] = 0.f;
    #pragma unroll
    for (int d = 0; d < BSZ; ++d) {
        const half8 hv = *(const half8*)&H[(pos + d) * RS_H + c8 * 8];
        #pragma unroll
        for (int k = 0; k < 8; ++k) acc[k] += (float)hv[k];
    }
    #pragma unroll
    for (int j = 0; j < 3; ++j) {
        half8 o;
        #pragma unroll
        for (int k = 0; k < 8; ++k) o[k] = (half_t)acc[k];
        *(half8*)(ws2 + (((size_t)(z * DIM + pos) * DIM + x) * NBINS + c8 * 8)) = o;
        if (j < 2) {
            const half8 hs = *(const half8*)&H[pos * RS_H + c8 * 8];
            const half8 ha = *(const half8*)&H[(pos + BSZ) * RS_H + c8 * 8];
            #pragma unroll
            for (int k = 0; k < 8; ++k) acc[k] += (float)ha[k] - (float)hs[k];
            ++pos;
        }
    }
}

// ===========================================================================
// K3h: z-window, fp16 ws2 -> f32 out. Block per (x=bx, y=by), line = 96 z.
// ===========================================================================
__global__ __launch_bounds__(NTHREADS) void k3_zsum_h(
    const half_t* __restrict__ ws2, float* __restrict__ out)
{
    __shared__ half_t H[PADROWS * RS_H];
    const int tid = threadIdx.x;
    const int x = blockIdx.x, y = blockIdx.y;

    for (int i = tid; i < DIM * 8; i += NTHREADS) {
        const int pos = i >> 3, c8 = i & 7;
        *(half8*)&H[pos * RS_H + c8 * 8] =
            *(const half8*)(ws2 + (((size_t)(pos * DIM + y) * DIM + x) * NBINS + c8 * 8));
    }
    for (int i = tid; i < (PADROWS - DIM) * 8; i += NTHREADS) {
        const int pos = DIM + (i >> 3), c8 = i & 7;
        half8 zv = {};
        *(half8*)&H[pos * RS_H + c8 * 8] = zv;
    }
    __syncthreads();

    const int c4 = tid & 15;             // float4 output unit
    const int strip = tid >> 4;          // 0..15, 6 pos each
    int pos = strip * 6;

    float4 s = make_float4(0.f, 0.f, 0.f, 0.f);
    #pragma unroll
    for (int d = 0; d < BSZ; ++d) {
        const half4 hv = *(const half4*)&H[(pos + d) * RS_H + c4 * 4];
        s.x += (float)hv[0]; s.y += (float)hv[1];
        s.z += (float)hv[2]; s.w += (float)hv[3];
    }
    float4* out4 = (float4*)out;
    #pragma unroll
    for (int j = 0; j < 6; ++j) {
        out4[((size_t)(pos * DIM + y) * DIM + x) * 16 + c4] = s;
        if (j < 5) {
            const half4 hs = *(const half4*)&H[pos * RS_H + c4 * 4];
            const half4 ha = *(const half4*)&H[(pos + BSZ) * RS_H + c4 * 4];
            s.x += (float)ha[0] - (float)hs[0]; s.y += (float)ha[1] - (float)hs[1];
            s.z += (float)ha[2] - (float)hs[2]; s.w += (float)ha[3] - (float)hs[3];
            ++pos;
        }
    }
}

// ===========================================================================
// Fallback (ws too small): exact R3 f32 path, in place on out.
// ===========================================================================
__global__ __launch_bounds__(NTHREADS) void k1_bin_xsum_f(
    const float* __restrict__ in, float* __restrict__ out)
{
    __shared__ float V[PADROWS * RS_F];
    const int tid = threadIdx.x;
    const int y = blockIdx.x, z = blockIdx.y;

    for (int i = tid; i < PADROWS * RS4_F; i += NTHREADS)
        ((float4*)V)[i] = make_float4(0.f, 0.f, 0.f, 0.f);
    __syncthreads();
    bin_line_to_lds(in, V, y, z, tid);
    __syncthreads();

    const int c4 = tid & 15;
    const int strip = tid >> 4;
    int pos = strip * 6;
    const float4* V4 = (const float4*)V;

    float4 s = make_float4(0.f, 0.f, 0.f, 0.f);
    #pragma unroll
    for (int d = 0; d < BSZ; ++d) {
        const float4 v = V4[(pos + d) * RS4_F + c4];
        s.x += v.x; s.y += v.y; s.z += v.z; s.w += v.w;
    }
    float4* out4 = (float4*)out;
    const int base = (z * DIM + y) * DIM * 16;
    out4[base + pos * 16 + c4] = s;
    #pragma unroll
    for (int j = 1; j < 6; ++j) {
        const float4 a = V4[pos * RS4_F + c4];
        const float4 b = V4[(pos + BSZ) * RS4_F + c4];
        s.x += b.x - a.x; s.y += b.y - a.y; s.z += b.z - a.z; s.w += b.w - a.w;
        ++pos;
        out4[base + pos * 16 + c4] = s;
    }
}

__global__ __launch_bounds__(NTHREADS) void k_axis_sum_f(
    float* __restrict__ data, const int mulY, const int stride4)
{
    __shared__ float4 V4[PADROWS * RS4_F];
    const int tid = threadIdx.x;
    const int base4 = (blockIdx.y * mulY + blockIdx.x) * 16;
    float4* data4 = (float4*)data;

    for (int i = tid; i < DIM * 16; i += NTHREADS) {
        const int pos = i >> 4, c4 = i & 15;
        V4[pos * RS4_F + c4] = data4[base4 + (size_t)pos * stride4 + c4];
    }
    for (int i = tid; i < (PADROWS - DIM) * 16; i += NTHREADS) {
        const int pos = DIM + (i >> 4), c4 = i & 15;
        V4[pos * RS4_F + c4] = make_float4(0.f, 0.f, 0.f, 0.f);
    }
    __syncthreads();

    const int c4 = tid & 15;
    const int strip = tid >> 4;
    int pos = strip * 6;

    float4 s = make_float4(0.f, 0.f, 0.f, 0.f);
    #pragma unroll
    for (int d = 0; d < BSZ; ++d) {
        const float4 v = V4[(pos + d) * RS4_F + c4];
        s.x += v.x; s.y += v.y; s.z += v.z; s.w += v.w;
    }
    data4[base4 + (size_t)pos * stride4 + c4] = s;
    #pragma unroll
    for (int j = 1; j < 6; ++j) {
        const float4 a = V4[pos * RS4_F + c4];
        const float4 b = V4[(pos + BSZ) * RS4_F + c4];
        s.x += b.x - a.x; s.y += b.y - a.y; s.z += b.z - a.z; s.w += b.w - a.w;
        ++pos;
        data4[base4 + (size_t)pos * stride4 + c4] = s;
    }
}

extern "C" void kernel_launch(void* const* d_in, const int* in_sizes, int n_in,
                              void* d_out, int out_size, void* d_ws, size_t ws_size,
                              hipStream_t stream) {
    (void)in_sizes; (void)n_in; (void)out_size;
    const float* x = (const float*)d_in[0];
    float* out = (float*)d_out;
    const size_t nvox = (size_t)DIM * DIM * DIM * NBINS;   // 56,623,104
    const size_t need = 2 * nvox * sizeof(half_t);         // 226.5 MB

    dim3 grid(DIM, DIM), block(NTHREADS);
    if (ws_size >= need) {
        half_t* ws1 = (half_t*)d_ws;
        half_t* ws2 = ws1 + nvox;
        k1_bin_xsum_h<<<grid, block, 0, stream>>>(x, ws1);
        k2_ysum_h<<<grid, block, 0, stream>>>(ws1, ws2);
        k3_zsum_h<<<grid, block, 0, stream>>>(ws2, out);
    } else {
        k1_bin_xsum_f<<<grid, block, 0, stream>>>(x, out);
        k_axis_sum_f<<<grid, block, 0, stream>>>(out, DIM * DIM * 16, DIM * 16);
        k_axis_sum_f<<<grid, block, 0, stream>>>(out, DIM * 16, DIM * DIM * 16);
    }
}

// Round 7
// 326.896 us; speedup vs baseline: 1.4007x; 1.0263x over previous
//
#include <hip/hip_runtime.h>

typedef _Float16 half_t;
typedef __attribute__((ext_vector_type(8))) _Float16 half8;
typedef __attribute__((ext_vector_type(4))) _Float16 half4;

#define DIM 96
#define NBINS 64
#define BSZ 15
#define PADROWS (DIM + BSZ - 1)   /* 110 */
#define NTHREADS 256
#define RS_F 68                   /* f32 LDS row stride in floats (64+4 pad) */
#define RS4_F 17                  /* same, in float4 */
#define RS_H 72                   /* f16 LDS row stride in halves (64+8 pad) */
#define TY 4                      /* out rows per block in fused kernel */
#define YTILES (DIM / TY)         /* 24 */

// ===========================================================================
// Gradient + faithful soft-binning of voxel (z,ys,x=lane) scatter-added
// (sgn=+1) or -subtracted (sgn=-1) into LDS row V[x*RS_F + bin].
// Lane x touches ONLY row x -> no cross-lane races, no barrier needed.
// ===========================================================================
__device__ __forceinline__ void bin_line_scatter(
    const float* __restrict__ in, float* __restrict__ V,
    const int y, const int z, const int tid, const float sgn)
{
    if (tid < DIM) {
        const int x = tid;
        const int idx = (z * DIM + y) * DIM + x;
        const float xm = (x > 0)       ? in[idx - 1]         : 0.0f;
        const float xp = (x < DIM - 1) ? in[idx + 1]         : 0.0f;
        const float ym = (y > 0)       ? in[idx - DIM]       : 0.0f;
        const float yp = (y < DIM - 1) ? in[idx + DIM]       : 0.0f;
        const float zm = (z > 0)       ? in[idx - DIM * DIM] : 0.0f;
        const float zp = (z < DIM - 1) ? in[idx + DIM * DIM] : 0.0f;
        const float gx = xp - xm, gy = yp - ym, gz = zp - zm;

        const float EPSF  = 2.220446049250313e-16f;
        const float TWOPI = 6.28318530717958647692f;
        const float PIF   = 3.14159265358979323846f;

        const float r = sqrtf(gx * gx + gy * gy + gz * gz);
        float theta = atanf(gy / (gx + EPSF));
        const float phi = acosf(gz / (r + EPSF));
        if (theta < 0.0f) theta += TWOPI;
        const float t_raw = theta / (TWOPI / 8.0f);
        const float p_raw = phi   / (PIF   / 8.0f);
        const float ft = floorf(t_raw);
        const float fp = floorf(p_raw);
        int lt = (int)ft; if (lt == 8) lt = 0;
        int lp = (int)fp; if (lp == 8) lp = 0;
        const int ht = (lt + 1) & 7;
        const int hp = (lp + 1) & 7;
        const float frac  = t_raw - ft;
        const float w_lo  = fminf(frac, 1.0f - frac);
        const float w_hi  = 1.0f - w_lo;
        const float wp_lo = (frac == 0.0f) ? 1.0f : w_lo;  // faithful: theta frac gates phi split
        const float wp_hi = 1.0f - wp_lo;

        const float rs = r * sgn;
        float* vrow = V + x * RS_F;
        vrow[lt * 8 + lp] += rs * w_lo * wp_lo;
        vrow[ht * 8 + lp] += rs * w_hi * wp_lo;
        vrow[lt * 8 + hp] += rs * w_lo * wp_hi;
        vrow[ht * 8 + hp] += rs * w_hi * wp_hi;
    }
}

// ===========================================================================
// KA: fused bin + x-window + y-window -> fp16 ws1[z][y][x][64].
// Block per (ytile, z). LDS plane S[x][bin] holds sum of binned lines
// [y, y+14] (y-window); per out-row we x-window S with the running trick.
// y advances by scatter-add of line y+14 and scatter-subtract of line y
// (recomputed binning, bitwise-identical contributions).
// ===========================================================================
__global__ __launch_bounds__(NTHREADS) void kA_bin_xy_h(
    const float* __restrict__ in, half_t* __restrict__ ws1)
{
    __shared__ float V[PADROWS * RS_F];
    const int tid = threadIdx.x;
    const int y0 = blockIdx.x * TY;
    const int z  = blockIdx.y;

    // zero everything once (rows 96..109 stay zero forever: x-window pad)
    for (int i = tid; i < PADROWS * RS4_F; i += NTHREADS)
        ((float4*)V)[i] = make_float4(0.f, 0.f, 0.f, 0.f);
    __syncthreads();

    // prologue: S = sum of binned lines y0 .. y0+13 (clamped). Lane-local.
    #pragma unroll
    for (int j = 0; j < BSZ - 1; ++j) {
        const int ys = y0 + j;
        if (ys < DIM) bin_line_scatter(in, V, ys, z, tid, 1.0f);
    }

    const int c8 = tid & 7;              // 8 bins (one half8)
    const int strip = tid >> 3;          // 0..31, 3 positions each
    const int pos0 = strip * 3;
    const float4* V4 = (const float4*)V;

    for (int r = 0; r < TY; ++r) {
        const int y = y0 + r;
        if (y + BSZ - 1 < DIM) bin_line_scatter(in, V, y + BSZ - 1, z, tid, 1.0f);
        __syncthreads();                 // S complete for row y, visible to all

        // x-window of S via running window over pos0..pos0+2
        float acc[8];
        #pragma unroll
        for (int k = 0; k < 8; ++k) acc[k] = 0.f;
        #pragma unroll
        for (int d = 0; d < BSZ; ++d) {
            const float4 a = V4[(pos0 + d) * RS4_F + c8 * 2];
            const float4 b = V4[(pos0 + d) * RS4_F + c8 * 2 + 1];
            acc[0] += a.x; acc[1] += a.y; acc[2] += a.z; acc[3] += a.w;
            acc[4] += b.x; acc[5] += b.y; acc[6] += b.z; acc[7] += b.w;
        }
        int pos = pos0;
        #pragma unroll
        for (int j = 0; j < 3; ++j) {
            half8 o;
            #pragma unroll
            for (int k = 0; k < 8; ++k) o[k] = (half_t)acc[k];
            *(half8*)(ws1 + (((size_t)(z * DIM + y) * DIM + pos) * NBINS + c8 * 8)) = o;
            if (j < 2) {
                const float4 a0 = V4[pos * RS4_F + c8 * 2];
                const float4 b0 = V4[pos * RS4_F + c8 * 2 + 1];
                const float4 a1 = V4[(pos + BSZ) * RS4_F + c8 * 2];
                const float4 b1 = V4[(pos + BSZ) * RS4_F + c8 * 2 + 1];
                acc[0] += a1.x - a0.x; acc[1] += a1.y - a0.y;
                acc[2] += a1.z - a0.z; acc[3] += a1.w - a0.w;
                acc[4] += b1.x - b0.x; acc[5] += b1.y - b0.y;
                acc[6] += b1.z - b0.z; acc[7] += b1.w - b0.w;
                ++pos;
            }
        }
        __syncthreads();                 // all reads of S done
        if (r < TY - 1)                  // slide window: drop line y
            bin_line_scatter(in, V, y, z, tid, -1.0f);
    }
}

// ===========================================================================
// K3h: z-window, fp16 ws1 -> f32 out. Block per (x=bx, y=by), line = 96 z.
// (byte-identical to the R6 kernel that passed)
// ===========================================================================
__global__ __launch_bounds__(NTHREADS) void k3_zsum_h(
    const half_t* __restrict__ ws2, float* __restrict__ out)
{
    __shared__ half_t H[PADROWS * RS_H];
    const int tid = threadIdx.x;
    const int x = blockIdx.x, y = blockIdx.y;

    for (int i = tid; i < DIM * 8; i += NTHREADS) {
        const int pos = i >> 3, c8 = i & 7;
        *(half8*)&H[pos * RS_H + c8 * 8] =
            *(const half8*)(ws2 + (((size_t)(pos * DIM + y) * DIM + x) * NBINS + c8 * 8));
    }
    for (int i = tid; i < (PADROWS - DIM) * 8; i += NTHREADS) {
        const int pos = DIM + (i >> 3), c8 = i & 7;
        half8 zv = {};
        *(half8*)&H[pos * RS_H + c8 * 8] = zv;
    }
    __syncthreads();

    const int c4 = tid & 15;             // float4 output unit
    const int strip = tid >> 4;          // 0..15, 6 pos each
    int pos = strip * 6;

    float4 s = make_float4(0.f, 0.f, 0.f, 0.f);
    #pragma unroll
    for (int d = 0; d < BSZ; ++d) {
        const half4 hv = *(const half4*)&H[(pos + d) * RS_H + c4 * 4];
        s.x += (float)hv[0]; s.y += (float)hv[1];
        s.z += (float)hv[2]; s.w += (float)hv[3];
    }
    float4* out4 = (float4*)out;
    #pragma unroll
    for (int j = 0; j < 6; ++j) {
        out4[((size_t)(pos * DIM + y) * DIM + x) * 16 + c4] = s;
        if (j < 5) {
            const half4 hs = *(const half4*)&H[pos * RS_H + c4 * 4];
            const half4 ha = *(const half4*)&H[(pos + BSZ) * RS_H + c4 * 4];
            s.x += (float)ha[0] - (float)hs[0]; s.y += (float)ha[1] - (float)hs[1];
            s.z += (float)ha[2] - (float)hs[2]; s.w += (float)ha[3] - (float)hs[3];
            ++pos;
        }
    }
}

// ===========================================================================
// Fallback (ws too small): R3/R6 f32 path, in place on out.
// ===========================================================================
__global__ __launch_bounds__(NTHREADS) void k1_bin_xsum_f(
    const float* __restrict__ in, float* __restrict__ out)
{
    __shared__ float V[PADROWS * RS_F];
    const int tid = threadIdx.x;
    const int y = blockIdx.x, z = blockIdx.y;

    for (int i = tid; i < PADROWS * RS4_F; i += NTHREADS)
        ((float4*)V)[i] = make_float4(0.f, 0.f, 0.f, 0.f);
    __syncthreads();
    bin_line_scatter(in, V, y, z, tid, 1.0f);
    __syncthreads();

    const int c4 = tid & 15;
    const int strip = tid >> 4;
    int pos = strip * 6;
    const float4* V4 = (const float4*)V;

    float4 s = make_float4(0.f, 0.f, 0.f, 0.f);
    #pragma unroll
    for (int d = 0; d < BSZ; ++d) {
        const float4 v = V4[(pos + d) * RS4_F + c4];
        s.x += v.x; s.y += v.y; s.z += v.z; s.w += v.w;
    }
    float4* out4 = (float4*)out;
    const int base = (z * DIM + y) * DIM * 16;
    out4[base + pos * 16 + c4] = s;
    #pragma unroll
    for (int j = 1; j < 6; ++j) {
        const float4 a = V4[pos * RS4_F + c4];
        const float4 b = V4[(pos + BSZ) * RS4_F + c4];
        s.x += b.x - a.x; s.y += b.y - a.y; s.z += b.z - a.z; s.w += b.w - a.w;
        ++pos;
        out4[base + pos * 16 + c4] = s;
    }
}

__global__ __launch_bounds__(NTHREADS) void k_axis_sum_f(
    float* __restrict__ data, const int mulY, const int stride4)
{
    __shared__ float4 V4[PADROWS * RS4_F];
    const int tid = threadIdx.x;
    const int base4 = (blockIdx.y * mulY + blockIdx.x) * 16;
    float4* data4 = (float4*)data;

    for (int i = tid; i < DIM * 16; i += NTHREADS) {
        const int pos = i >> 4, c4 = i & 15;
        V4[pos * RS4_F + c4] = data4[base4 + (size_t)pos * stride4 + c4];
    }
    for (int i = tid; i < (PADROWS - DIM) * 16; i += NTHREADS) {
        const int pos = DIM + (i >> 4), c4 = i & 15;
        V4[pos * RS4_F + c4] = make_float4(0.f, 0.f, 0.f, 0.f);
    }
    __syncthreads();

    const int c4 = tid & 15;
    const int strip = tid >> 4;
    int pos = strip * 6;

    float4 s = make_float4(0.f, 0.f, 0.f, 0.f);
    #pragma unroll
    for (int d = 0; d < BSZ; ++d) {
        const float4 v = V4[(pos + d) * RS4_F + c4];
        s.x += v.x; s.y += v.y; s.z += v.z; s.w += v.w;
    }
    data4[base4 + (size_t)pos * stride4 + c4] = s;
    #pragma unroll
    for (int j = 1; j < 6; ++j) {
        const float4 a = V4[pos * RS4_F + c4];
        const float4 b = V4[(pos + BSZ) * RS4_F + c4];
        s.x += b.x - a.x; s.y += b.y - a.y; s.z += b.z - a.z; s.w += b.w - a.w;
        ++pos;
        data4[base4 + (size_t)pos * stride4 + c4] = s;
    }
}

extern "C" void kernel_launch(void* const* d_in, const int* in_sizes, int n_in,
                              void* d_out, int out_size, void* d_ws, size_t ws_size,
                              hipStream_t stream) {
    (void)in_sizes; (void)n_in; (void)out_size;
    const float* x = (const float*)d_in[0];
    float* out = (float*)d_out;
    const size_t nvox = (size_t)DIM * DIM * DIM * NBINS;   // 56,623,104
    const size_t need = nvox * sizeof(half_t);             // 113.2 MB

    dim3 block(NTHREADS);
    if (ws_size >= need) {
        half_t* ws1 = (half_t*)d_ws;
        // Fused bin + x-window + y-window -> ws1 (fp16)
        kA_bin_xy_h<<<dim3(YTILES, DIM), block, 0, stream>>>(x, ws1);
        // z-window -> out (f32)
        k3_zsum_h<<<dim3(DIM, DIM), block, 0, stream>>>(ws1, out);
    } else {
        k1_bin_xsum_f<<<dim3(DIM, DIM), block, 0, stream>>>(x, out);
        k_axis_sum_f<<<dim3(DIM, DIM), block, 0, stream>>>(out, DIM * DIM * 16, DIM * 16);
        k_axis_sum_f<<<dim3(DIM, DIM), block, 0, stream>>>(out, DIM * 16, DIM * DIM * 16);
    }
}